// Round 2
// baseline (356.783 us; speedup 1.0000x reference)
//
#include <hip/hip_runtime.h>

typedef __bf16 bf16;
typedef __bf16 bf16x4 __attribute__((ext_vector_type(4)));
typedef __bf16 bf16x8 __attribute__((ext_vector_type(8)));
typedef float  f32x4  __attribute__((ext_vector_type(4)));

#define TOKENS 16384
#define D_IN   4096
#define D_OUT  4096
#define RANK   512

// Async global->LDS, 16B per lane. LDS dest must be wave-uniform base + lane*16.
__device__ inline void gload_lds16(const bf16* g, bf16* l) {
    __builtin_amdgcn_global_load_lds((const __attribute__((address_space(1))) void*)g,
                                     (__attribute__((address_space(3))) void*)l,
                                     16, 0, 0);
}

// ---------------------------------------------------------------------------
// Prep kernel 1: Vst[r][k] = bf16(V[k][r] * sigma[r])   (transpose + scale)
// ---------------------------------------------------------------------------
__global__ __launch_bounds__(256) void vt_scale(const float* __restrict__ V,
                                                const float* __restrict__ sg,
                                                bf16* __restrict__ Vst) {
    __shared__ float tile[64][65];
    const int tx = threadIdx.x & 63;
    const int ty = threadIdx.x >> 6;
    const int kb = blockIdx.x * 64;         // over D_IN
    const int rb = blockIdx.y * 64;         // over RANK
    const float s = sg[rb + tx];
#pragma unroll
    for (int i = ty; i < 64; i += 4)
        tile[i][tx] = V[(size_t)(kb + i) * RANK + rb + tx] * s;
    __syncthreads();
#pragma unroll
    for (int i = ty; i < 64; i += 4)
        Vst[(size_t)(rb + i) * D_IN + kb + tx] = (bf16)tile[tx][i];
}

// ---------------------------------------------------------------------------
// Prep kernel 2: elementwise f32 -> bf16
// ---------------------------------------------------------------------------
__global__ __launch_bounds__(256) void cvt_bf16_4(const float* __restrict__ in,
                                                  bf16* __restrict__ o, int n4) {
    int i = blockIdx.x * 256 + threadIdx.x;
    if (i < n4) {
        f32x4 v = *(const f32x4*)(in + (size_t)i * 4);
        bf16x4 b = { (bf16)v[0], (bf16)v[1], (bf16)v[2], (bf16)v[3] };
        *(bf16x4*)(o + (size_t)i * 4) = b;
    }
}

// ---------------------------------------------------------------------------
// GEMM1: T[M][N] = bf16( A_f32[M][K] @ B_bf16[N][K]^T )
//   BM=64, BN=128, BK=64, 256 threads = 4 waves (2x2), wave tile 32x64
//   = 2x4 frags of mfma_f32_16x16x32_bf16. Grid = (M/64)*(N/128) = 1024
//   blocks -> 4 blocks/CU (occupancy fix vs the 128x128 version's 2/CU).
// ---------------------------------------------------------------------------
__global__ __launch_bounds__(256) void gemm1_xa(const float* __restrict__ A,
                                                const bf16* __restrict__ B,
                                                bf16* __restrict__ T,
                                                int M, int N, int K) {
    __shared__ bf16 Al[64 * 64];    //  8 KB
    __shared__ bf16 Bl[128 * 64];   // 16 KB

    const int t  = threadIdx.x;
    const int l  = t & 63;
    const int w  = t >> 6;
    const int wr = w >> 1, wc = w & 1;
    const int lr = l & 15;
    const int kg = l >> 4;

    // XCD-aware bijective swizzle (nwg % 8 == 0)
    const int nwg = gridDim.x;
    const int bid = blockIdx.x;
    const int cpx = nwg >> 3;
    const int swz = (bid & 7) * cpx + (bid >> 3);
    const int ntn = N >> 7;
    const int tm  = (swz / ntn) * 64;
    const int tn  = (swz % ntn) * 128;

    f32x4 acc[2][4] = {};

    for (int kt = 0; kt < K; kt += 64) {
        // ---- stage A tile [64][64]: f32 load -> bf16 cvt -> LDS ----
#pragma unroll
        for (int c = 0; c < 4; ++c) {
            int j = c * 256 + t;
            int row = j >> 4, cg = j & 15;
            f32x4 v = *(const f32x4*)(A + (size_t)(tm + row) * K + kt + cg * 4);
            bf16x4 b = { (bf16)v[0], (bf16)v[1], (bf16)v[2], (bf16)v[3] };
            *(bf16x4*)&Al[row * 64 + cg * 4] = b;
        }
        // ---- stage B tile [128][64] via global_load_lds ----
#pragma unroll
        for (int c = 0; c < 4; ++c) {
            int i = c * 256 + t;
            gload_lds16(B + (size_t)(tn + (i >> 3)) * K + kt + (i & 7) * 8, &Bl[i * 8]);
        }
        __syncthreads();

#pragma unroll
        for (int ks = 0; ks < 2; ++ks) {
            bf16x8 af[2], bfr[4];
#pragma unroll
            for (int f = 0; f < 2; ++f)
                af[f]  = *(const bf16x8*)&Al[(wr * 32 + f * 16 + lr) * 64 + ks * 32 + kg * 8];
#pragma unroll
            for (int f = 0; f < 4; ++f)
                bfr[f] = *(const bf16x8*)&Bl[(wc * 64 + f * 16 + lr) * 64 + ks * 32 + kg * 8];
#pragma unroll
            for (int fm = 0; fm < 2; ++fm)
#pragma unroll
                for (int fn = 0; fn < 4; ++fn)
                    acc[fm][fn] = __builtin_amdgcn_mfma_f32_16x16x32_bf16(
                        af[fm], bfr[fn], acc[fm][fn], 0, 0, 0);
        }
        __syncthreads();
    }

    // ---- epilogue: C/D layout col = lane&15, row = (lane>>4)*4 + reg ----
    const int r0 = tm + wr * 32 + kg * 4;
    const int c0 = tn + wc * 64 + lr;
#pragma unroll
    for (int fm = 0; fm < 2; ++fm)
#pragma unroll
        for (int fn = 0; fn < 4; ++fn)
#pragma unroll
            for (int r = 0; r < 4; ++r)
                T[(size_t)(r0 + fm * 16 + r) * N + (c0 + fn * 16)] = (bf16)acc[fm][fn][r];
}

// ---------------------------------------------------------------------------
// GEMM2 (m97 structure, unchanged): C_f32[M][N] = A_bf16[M][K] @ B_bf16[N][K]^T
//   128x128 tile, BK=64, 4 waves (2x2), wave 64x64 = 4x4 frags.
// ---------------------------------------------------------------------------
__global__ __launch_bounds__(256) void gemm2_bt(const bf16* __restrict__ A,
                                                const bf16* __restrict__ B,
                                                float* __restrict__ out,
                                                int M, int N, int K) {
    __shared__ bf16 Al[128 * 64];
    __shared__ bf16 Bl[128 * 64];

    const int t  = threadIdx.x;
    const int l  = t & 63;
    const int w  = t >> 6;
    const int wr = w >> 1, wc = w & 1;
    const int lr = l & 15;
    const int kg = l >> 4;

    const int nwg = gridDim.x;
    const int bid = blockIdx.x;
    const int cpx = nwg >> 3;
    const int swz = (bid & 7) * cpx + (bid >> 3);
    const int ntn = N >> 7;
    const int tm  = (swz / ntn) << 7;
    const int tn  = (swz % ntn) << 7;

    f32x4 acc[4][4] = {};

    for (int kt = 0; kt < K; kt += 64) {
#pragma unroll
        for (int c = 0; c < 4; ++c) {
            int i = c * 256 + t;
            gload_lds16(A + (size_t)(tm + (i >> 3)) * K + kt + (i & 7) * 8, &Al[i * 8]);
        }
#pragma unroll
        for (int c = 0; c < 4; ++c) {
            int i = c * 256 + t;
            gload_lds16(B + (size_t)(tn + (i >> 3)) * K + kt + (i & 7) * 8, &Bl[i * 8]);
        }
        __syncthreads();

#pragma unroll
        for (int ks = 0; ks < 2; ++ks) {
            bf16x8 af[4], bfr[4];
#pragma unroll
            for (int f = 0; f < 4; ++f) {
                af[f]  = *(const bf16x8*)&Al[(wr * 64 + f * 16 + lr) * 64 + ks * 32 + kg * 8];
                bfr[f] = *(const bf16x8*)&Bl[(wc * 64 + f * 16 + lr) * 64 + ks * 32 + kg * 8];
            }
#pragma unroll
            for (int fm = 0; fm < 4; ++fm)
#pragma unroll
                for (int fn = 0; fn < 4; ++fn)
                    acc[fm][fn] = __builtin_amdgcn_mfma_f32_16x16x32_bf16(
                        af[fm], bfr[fn], acc[fm][fn], 0, 0, 0);
        }
        __syncthreads();
    }

    const int r0 = tm + wr * 64 + kg * 4;
    const int c0 = tn + wc * 64 + lr;
#pragma unroll
    for (int fm = 0; fm < 4; ++fm)
#pragma unroll
        for (int fn = 0; fn < 4; ++fn)
#pragma unroll
            for (int r = 0; r < 4; ++r)
                out[(size_t)(r0 + fm * 16 + r) * N + (c0 + fn * 16)] = acc[fm][fn][r];
}

// ---------------------------------------------------------------------------
extern "C" void kernel_launch(void* const* d_in, const int* in_sizes, int n_in,
                              void* d_out, int out_size, void* d_ws, size_t ws_size,
                              hipStream_t stream) {
    const float* x  = (const float*)d_in[0];  // [16384][4096]
    const float* U  = (const float*)d_in[1];  // [4096][512]
    const float* sg = (const float*)d_in[2];  // [512]
    const float* V  = (const float*)d_in[3];  // [4096][512]
    float* out = (float*)d_out;               // [16384][4096] f32

    char* ws = (char*)d_ws;
    bf16* Vst = (bf16*)ws;                    // [512][4096]  = 4 MB
    bf16* Ub  = (bf16*)(ws + (4u << 20));     // [4096][512]  = 4 MB
    bf16* T   = (bf16*)(ws + (8u << 20));     // [16384][512] = 16 MB

    vt_scale<<<dim3(D_IN / 64, RANK / 64), 256, 0, stream>>>(V, sg, Vst);
    cvt_bf16_4<<<(D_OUT * RANK / 4 + 255) / 256, 256, 0, stream>>>(U, Ub, D_OUT * RANK / 4);

    // GEMM1: T = bf16( x @ Vst^T ), grid 256*4 = 1024 blocks (4/CU)
    gemm1_xa<<<(TOKENS / 64) * (RANK / 128), 256, 0, stream>>>(
        x, Vst, T, TOKENS, RANK, D_IN);

    // GEMM2: out = T @ Ub^T (f32 out), grid 128*32 = 4096 blocks
    gemm2_bt<<<(TOKENS / 128) * (D_OUT / 128), 256, 0, stream>>>(
        T, Ub, out, TOKENS, D_OUT, RANK);
}

// Round 3
// 310.332 us; speedup vs baseline: 1.1497x; 1.1497x over previous
//
#include <hip/hip_runtime.h>

typedef __bf16 bf16;
typedef __bf16 bf16x4 __attribute__((ext_vector_type(4)));
typedef __bf16 bf16x8 __attribute__((ext_vector_type(8)));
typedef float  f32x4  __attribute__((ext_vector_type(4)));

#define TOKENS 16384
#define D_IN   4096
#define D_OUT  4096
#define RANK   512

// Async global->LDS, 16B per lane. LDS dest must be wave-uniform base + lane*16.
__device__ inline void gload_lds16(const bf16* g, bf16* l) {
    __builtin_amdgcn_global_load_lds((const __attribute__((address_space(1))) void*)g,
                                     (__attribute__((address_space(3))) void*)l,
                                     16, 0, 0);
}

// ---------------------------------------------------------------------------
// Prep 1: Vst[r][k'] = bf16(V[k][r] * sigma[r]), PRE-SWIZZLED for GEMM1's LDS:
//   within each 64-k block, 16B-chunk index c -> c ^ (r&7). GEMM1 stages B via
//   global_load_lds (linear LDS dest), so the T2 bank-conflict swizzle must be
//   applied to the global source (rule: inverse-swz source + swz read).
// ---------------------------------------------------------------------------
__global__ __launch_bounds__(256) void vt_scale(const float* __restrict__ V,
                                                const float* __restrict__ sg,
                                                bf16* __restrict__ Vst) {
    __shared__ float tile[64][65];
    const int tx = threadIdx.x & 63;
    const int ty = threadIdx.x >> 6;
    const int kb = blockIdx.x * 64;         // over D_IN (multiple of 64)
    const int rb = blockIdx.y * 64;         // over RANK
    const float s = sg[rb + tx];
#pragma unroll
    for (int i = ty; i < 64; i += 4)
        tile[i][tx] = V[(size_t)(kb + i) * RANK + rb + tx] * s;
    __syncthreads();
#pragma unroll
    for (int i = ty; i < 64; i += 4) {
        int r = rb + i;
        int kp = kb + (tx ^ ((r & 7) << 3));     // swizzle 8-elem chunks
        Vst[(size_t)r * D_IN + kp] = (bf16)tile[tx][i];
    }
}

// ---------------------------------------------------------------------------
// Prep 2: elementwise f32 -> bf16 (U, layout unchanged)
// ---------------------------------------------------------------------------
__global__ __launch_bounds__(256) void cvt_bf16_4(const float* __restrict__ in,
                                                  bf16* __restrict__ o, int n4) {
    int i = blockIdx.x * 256 + threadIdx.x;
    if (i < n4) {
        f32x4 v = *(const f32x4*)(in + (size_t)i * 4);
        bf16x4 b = { (bf16)v[0], (bf16)v[1], (bf16)v[2], (bf16)v[3] };
        *(bf16x4*)(o + (size_t)i * 4) = b;
    }
}

// ---------------------------------------------------------------------------
// GEMM1: T[M][N] = bf16( A_f32[M][K] @ B_bf16[N][K]^T ), B pre-swizzled.
//   128x128 tile, BK=64, 4 waves (2x2), wave 64x64 = 4x4 frags 16x16x32.
//   Double-buffered LDS (64 KB), ONE raw barrier per K-step, next-tile
//   A-loads(->regs) + B global_load_lds issued BEFORE current MFMAs so HBM
//   latency hides under compute. LDS reads/writes XOR-swizzled (T2).
// ---------------------------------------------------------------------------
__global__ __launch_bounds__(256, 2) void gemm1_pipe(const float* __restrict__ A,
                                                     const bf16* __restrict__ B,
                                                     bf16* __restrict__ T,
                                                     int M, int N, int K) {
    __shared__ bf16 Al[2][128 * 64];
    __shared__ bf16 Bl[2][128 * 64];

    const int t  = threadIdx.x;
    const int l  = t & 63;
    const int w  = t >> 6;
    const int wr = w >> 1, wc = w & 1;
    const int lr = l & 15;
    const int kg = l >> 4;
    const int sxor = (l & 7) << 3;          // frag-read swizzle (row&7 == lr&7)

    // XCD-aware bijective swizzle (nwg=512, %8==0)
    const int nwg = gridDim.x;
    const int bid = blockIdx.x;
    const int cpx = nwg >> 3;
    const int swz = (bid & 7) * cpx + (bid >> 3);
    const int ntn = N >> 7;
    const int tm  = (swz / ntn) << 7;
    const int tn  = (swz % ntn) << 7;

    // A staging coords: j=c*256+t -> row=c*16+(t>>4), 16B chunk cg=t&15
    const int arow  = t >> 4;
    const int acg   = t & 15;
    const int awxor = (arow & 7) << 3;      // A ds_write swizzle (row&7 == arow&7)
    const float* Ap = A + (size_t)(tm + arow) * K + acg * 4;
    // B staging coords: i=c*256+t -> row=c*32+(t>>3), chunk t&7 (src pre-swizzled)
    const bf16* Bp  = B + (size_t)(tn + (t >> 3)) * K + (t & 7) * 8;

    f32x4 acc[4][4] = {};
    f32x4 ra[8];

    // ---- prologue: stage tile 0 ----
#pragma unroll
    for (int c = 0; c < 8; ++c)
        ra[c] = *(const f32x4*)(Ap + (size_t)(c * 16) * K);
#pragma unroll
    for (int c = 0; c < 4; ++c)
        gload_lds16(Bp + (size_t)(c * 32) * K, &Bl[0][(c * 256 + t) * 8]);
#pragma unroll
    for (int c = 0; c < 8; ++c) {
        bf16x4 b = { (bf16)ra[c][0], (bf16)ra[c][1], (bf16)ra[c][2], (bf16)ra[c][3] };
        *(bf16x4*)&Al[0][(c * 16 + arow) * 64 + ((acg * 4) ^ awxor)] = b;
    }
    asm volatile("s_waitcnt vmcnt(0) lgkmcnt(0)" ::: "memory");
    __builtin_amdgcn_s_barrier();

    int cb = 0;
    for (int kt = 0; kt < K - 64; kt += 64) {
        const int nb = cb ^ 1;
        // ---- issue next-tile loads first (hide under compute) ----
#pragma unroll
        for (int c = 0; c < 8; ++c)
            ra[c] = *(const f32x4*)(Ap + kt + 64 + (size_t)(c * 16) * K);
#pragma unroll
        for (int c = 0; c < 4; ++c)
            gload_lds16(Bp + kt + 64 + (size_t)(c * 32) * K, &Bl[nb][(c * 256 + t) * 8]);

        // ---- compute current tile ----
#pragma unroll
        for (int ks = 0; ks < 2; ++ks) {
            bf16x8 af[4], bfr[4];
#pragma unroll
            for (int f = 0; f < 4; ++f) {
                af[f]  = *(const bf16x8*)&Al[cb][(wr * 64 + f * 16 + lr) * 64 + ((ks * 32 + kg * 8) ^ sxor)];
                bfr[f] = *(const bf16x8*)&Bl[cb][(wc * 64 + f * 16 + lr) * 64 + ((ks * 32 + kg * 8) ^ sxor)];
            }
#pragma unroll
            for (int fm = 0; fm < 4; ++fm)
#pragma unroll
                for (int fn = 0; fn < 4; ++fn)
                    acc[fm][fn] = __builtin_amdgcn_mfma_f32_16x16x32_bf16(
                        af[fm], bfr[fn], acc[fm][fn], 0, 0, 0);
        }

        // ---- write-back next A tile (compiler waits ra's vmcnt) ----
#pragma unroll
        for (int c = 0; c < 8; ++c) {
            bf16x4 b = { (bf16)ra[c][0], (bf16)ra[c][1], (bf16)ra[c][2], (bf16)ra[c][3] };
            *(bf16x4*)&Al[nb][(c * 16 + arow) * 64 + ((acg * 4) ^ awxor)] = b;
        }
        asm volatile("s_waitcnt vmcnt(0) lgkmcnt(0)" ::: "memory");
        __builtin_amdgcn_s_barrier();
        cb = nb;
    }

    // ---- epilogue K-step: compute last tile ----
#pragma unroll
    for (int ks = 0; ks < 2; ++ks) {
        bf16x8 af[4], bfr[4];
#pragma unroll
        for (int f = 0; f < 4; ++f) {
            af[f]  = *(const bf16x8*)&Al[cb][(wr * 64 + f * 16 + lr) * 64 + ((ks * 32 + kg * 8) ^ sxor)];
            bfr[f] = *(const bf16x8*)&Bl[cb][(wc * 64 + f * 16 + lr) * 64 + ((ks * 32 + kg * 8) ^ sxor)];
        }
#pragma unroll
        for (int fm = 0; fm < 4; ++fm)
#pragma unroll
            for (int fn = 0; fn < 4; ++fn)
                acc[fm][fn] = __builtin_amdgcn_mfma_f32_16x16x32_bf16(
                    af[fm], bfr[fn], acc[fm][fn], 0, 0, 0);
    }

    // ---- C-write: col = lane&15, row = (lane>>4)*4 + reg ----
    const int r0 = tm + wr * 64 + kg * 4;
    const int c0 = tn + wc * 64 + lr;
#pragma unroll
    for (int fm = 0; fm < 4; ++fm)
#pragma unroll
        for (int fn = 0; fn < 4; ++fn)
#pragma unroll
            for (int r = 0; r < 4; ++r)
                T[(size_t)(r0 + fm * 16 + r) * N + (c0 + fn * 16)] = (bf16)acc[fm][fn][r];
}

// ---------------------------------------------------------------------------
// GEMM2 (unchanged control): C_f32[M][N] = A_bf16[M][K] @ B_bf16[N][K]^T
// ---------------------------------------------------------------------------
__global__ __launch_bounds__(256) void gemm2_bt(const bf16* __restrict__ A,
                                                const bf16* __restrict__ B,
                                                float* __restrict__ out,
                                                int M, int N, int K) {
    __shared__ bf16 Al[128 * 64];
    __shared__ bf16 Bl[128 * 64];

    const int t  = threadIdx.x;
    const int l  = t & 63;
    const int w  = t >> 6;
    const int wr = w >> 1, wc = w & 1;
    const int lr = l & 15;
    const int kg = l >> 4;

    const int nwg = gridDim.x;
    const int bid = blockIdx.x;
    const int cpx = nwg >> 3;
    const int swz = (bid & 7) * cpx + (bid >> 3);
    const int ntn = N >> 7;
    const int tm  = (swz / ntn) << 7;
    const int tn  = (swz % ntn) << 7;

    f32x4 acc[4][4] = {};

    for (int kt = 0; kt < K; kt += 64) {
#pragma unroll
        for (int c = 0; c < 4; ++c) {
            int i = c * 256 + t;
            gload_lds16(A + (size_t)(tm + (i >> 3)) * K + kt + (i & 7) * 8, &Al[i * 8]);
        }
#pragma unroll
        for (int c = 0; c < 4; ++c) {
            int i = c * 256 + t;
            gload_lds16(B + (size_t)(tn + (i >> 3)) * K + kt + (i & 7) * 8, &Bl[i * 8]);
        }
        __syncthreads();

#pragma unroll
        for (int ks = 0; ks < 2; ++ks) {
            bf16x8 af[4], bfr[4];
#pragma unroll
            for (int f = 0; f < 4; ++f) {
                af[f]  = *(const bf16x8*)&Al[(wr * 64 + f * 16 + lr) * 64 + ks * 32 + kg * 8];
                bfr[f] = *(const bf16x8*)&Bl[(wc * 64 + f * 16 + lr) * 64 + ks * 32 + kg * 8];
            }
#pragma unroll
            for (int fm = 0; fm < 4; ++fm)
#pragma unroll
                for (int fn = 0; fn < 4; ++fn)
                    acc[fm][fn] = __builtin_amdgcn_mfma_f32_16x16x32_bf16(
                        af[fm], bfr[fn], acc[fm][fn], 0, 0, 0);
        }
        __syncthreads();
    }

    const int r0 = tm + wr * 64 + kg * 4;
    const int c0 = tn + wc * 64 + lr;
#pragma unroll
    for (int fm = 0; fm < 4; ++fm)
#pragma unroll
        for (int fn = 0; fn < 4; ++fn)
#pragma unroll
            for (int r = 0; r < 4; ++r)
                out[(size_t)(r0 + fm * 16 + r) * N + (c0 + fn * 16)] = acc[fm][fn][r];
}

// ---------------------------------------------------------------------------
extern "C" void kernel_launch(void* const* d_in, const int* in_sizes, int n_in,
                              void* d_out, int out_size, void* d_ws, size_t ws_size,
                              hipStream_t stream) {
    const float* x  = (const float*)d_in[0];  // [16384][4096]
    const float* U  = (const float*)d_in[1];  // [4096][512]
    const float* sg = (const float*)d_in[2];  // [512]
    const float* V  = (const float*)d_in[3];  // [4096][512]
    float* out = (float*)d_out;               // [16384][4096] f32

    char* ws = (char*)d_ws;
    bf16* Vst = (bf16*)ws;                    // [512][4096]  = 4 MB (pre-swizzled)
    bf16* Ub  = (bf16*)(ws + (4u << 20));     // [4096][512]  = 4 MB
    bf16* T   = (bf16*)(ws + (8u << 20));     // [16384][512] = 16 MB

    vt_scale<<<dim3(D_IN / 64, RANK / 64), 256, 0, stream>>>(V, sg, Vst);
    cvt_bf16_4<<<(D_OUT * RANK / 4 + 255) / 256, 256, 0, stream>>>(U, Ub, D_OUT * RANK / 4);

    // GEMM1: T = bf16( x @ Vst^T ), grid 128*4 = 512 blocks (2/CU), pipelined
    gemm1_pipe<<<(TOKENS / 128) * (RANK / 128), 256, 0, stream>>>(
        x, Vst, T, TOKENS, RANK, D_IN);

    // GEMM2: out = T @ Ub^T (f32 out), grid 128*32 = 4096 blocks
    gemm2_bt<<<(TOKENS / 128) * (D_OUT / 128), 256, 0, stream>>>(
        T, Ub, out, TOKENS, D_OUT, RANK);
}

// Round 4
// 268.344 us; speedup vs baseline: 1.3296x; 1.1565x over previous
//
#include <hip/hip_runtime.h>

typedef __bf16 bf16;
typedef __bf16 bf16x4 __attribute__((ext_vector_type(4)));
typedef __bf16 bf16x8 __attribute__((ext_vector_type(8)));
typedef float  f32x4  __attribute__((ext_vector_type(4)));

#define TOKENS 16384
#define D_IN   4096
#define D_OUT  4096
#define RANK   512

// Async global->LDS, 16B per lane. LDS dest must be wave-uniform base + lane*16.
__device__ inline void gload_lds16(const bf16* g, bf16* l) {
    __builtin_amdgcn_global_load_lds((const __attribute__((address_space(1))) void*)g,
                                     (__attribute__((address_space(3))) void*)l,
                                     16, 0, 0);
}

// ---------------------------------------------------------------------------
// Prep 1: Vst[r][k'] = bf16(V[k][r] * sigma[r]), PRE-SWIZZLED for GEMM1's LDS
//   (verified round 3: conflicts -> 0, absmax unchanged).
//   Within each 64-k block, element index tx -> tx ^ ((r&7)<<3) permutes
//   8-elem (16B) chunks; GEMM1 reads fragments with the same XOR.
// ---------------------------------------------------------------------------
__global__ __launch_bounds__(256) void vt_scale(const float* __restrict__ V,
                                                const float* __restrict__ sg,
                                                bf16* __restrict__ Vst) {
    __shared__ float tile[64][65];
    const int tx = threadIdx.x & 63;
    const int ty = threadIdx.x >> 6;
    const int kb = blockIdx.x * 64;         // over D_IN
    const int rb = blockIdx.y * 64;         // over RANK
    const float s = sg[rb + tx];
#pragma unroll
    for (int i = ty; i < 64; i += 4)
        tile[i][tx] = V[(size_t)(kb + i) * RANK + rb + tx] * s;
    __syncthreads();
#pragma unroll
    for (int i = ty; i < 64; i += 4) {
        int r = rb + i;
        int kp = kb + (tx ^ ((r & 7) << 3));
        Vst[(size_t)r * D_IN + kp] = (bf16)tile[tx][i];
    }
}

// ---------------------------------------------------------------------------
// Prep 2: elementwise f32 -> bf16 (U, layout unchanged)
// ---------------------------------------------------------------------------
__global__ __launch_bounds__(256) void cvt_bf16_4(const float* __restrict__ in,
                                                  bf16* __restrict__ o, int n4) {
    int i = blockIdx.x * 256 + threadIdx.x;
    if (i < n4) {
        f32x4 v = *(const f32x4*)(in + (size_t)i * 4);
        bf16x4 b = { (bf16)v[0], (bf16)v[1], (bf16)v[2], (bf16)v[3] };
        *(bf16x4*)(o + (size_t)i * 4) = b;
    }
}

// ---------------------------------------------------------------------------
// GEMM1: T[M][N] = bf16( A_f32[M][K] @ B_bf16[N][K]^T ), B pre-swizzled.
//   ROUND-1 STRUCTURE (single-buffered 128x128, BK=64, two barriers/step —
//   the fastest measured) + ROUND-3 SWIZZLE (conflict-free, verified).
//   B gload_lds issued first so the DMA overlaps A's f32 reg round-trip.
// ---------------------------------------------------------------------------
__global__ __launch_bounds__(256) void gemm1_swz(const float* __restrict__ A,
                                                 const bf16* __restrict__ B,
                                                 bf16* __restrict__ T,
                                                 int M, int N, int K) {
    __shared__ bf16 Al[128 * 64];
    __shared__ bf16 Bl[128 * 64];

    const int t  = threadIdx.x;
    const int l  = t & 63;
    const int w  = t >> 6;
    const int wr = w >> 1, wc = w & 1;
    const int lr = l & 15;
    const int kg = l >> 4;
    const int sxor = (lr & 7) << 3;          // frag-read swizzle (row&7 == lr&7)

    // XCD-aware bijective swizzle (nwg=512, %8==0)
    const int nwg = gridDim.x;
    const int bid = blockIdx.x;
    const int cpx = nwg >> 3;
    const int swz = (bid & 7) * cpx + (bid >> 3);
    const int ntn = N >> 7;
    const int tm  = (swz / ntn) << 7;
    const int tn  = (swz % ntn) << 7;

    // A staging: row = c*16 + (t>>4), 16B chunk (t&15) of 4 f32
    const int arow  = t >> 4;
    const int acg   = t & 15;
    const int awxor = (arow & 7) << 3;       // (c*16+arow)&7 == arow&7
    const float* Ap = A + (size_t)(tm + arow) * K + acg * 4;
    // B staging: row = c*32 + (t>>3), 16B chunk t&7 (source pre-swizzled)
    const bf16* Bp  = B + (size_t)(tn + (t >> 3)) * K + (t & 7) * 8;

    f32x4 acc[4][4] = {};

    for (int kt = 0; kt < K; kt += 64) {
        // ---- B tile via async DMA first (overlaps A's reg round-trip) ----
#pragma unroll
        for (int c = 0; c < 4; ++c)
            gload_lds16(Bp + kt + (size_t)(c * 32) * K, &Bl[(c * 256 + t) * 8]);
        // ---- A tile: f32 load -> bf16 cvt -> swizzled ds_write ----
        f32x4 ra[8];
#pragma unroll
        for (int c = 0; c < 8; ++c)
            ra[c] = *(const f32x4*)(Ap + kt + (size_t)(c * 16) * K);
#pragma unroll
        for (int c = 0; c < 8; ++c) {
            bf16x4 b = { (bf16)ra[c][0], (bf16)ra[c][1], (bf16)ra[c][2], (bf16)ra[c][3] };
            *(bf16x4*)&Al[(c * 16 + arow) * 64 + ((acg * 4) ^ awxor)] = b;
        }
        __syncthreads();

#pragma unroll
        for (int ks = 0; ks < 2; ++ks) {
            bf16x8 af[4], bfr[4];
#pragma unroll
            for (int f = 0; f < 4; ++f) {
                af[f]  = *(const bf16x8*)&Al[(wr * 64 + f * 16 + lr) * 64 + ((ks * 32 + kg * 8) ^ sxor)];
                bfr[f] = *(const bf16x8*)&Bl[(wc * 64 + f * 16 + lr) * 64 + ((ks * 32 + kg * 8) ^ sxor)];
            }
#pragma unroll
            for (int fm = 0; fm < 4; ++fm)
#pragma unroll
                for (int fn = 0; fn < 4; ++fn)
                    acc[fm][fn] = __builtin_amdgcn_mfma_f32_16x16x32_bf16(
                        af[fm], bfr[fn], acc[fm][fn], 0, 0, 0);
        }
        __syncthreads();
    }

    // ---- C-write: col = lane&15, row = (lane>>4)*4 + reg ----
    const int r0 = tm + wr * 64 + kg * 4;
    const int c0 = tn + wc * 64 + lr;
#pragma unroll
    for (int fm = 0; fm < 4; ++fm)
#pragma unroll
        for (int fn = 0; fn < 4; ++fn)
#pragma unroll
            for (int r = 0; r < 4; ++r)
                T[(size_t)(r0 + fm * 16 + r) * N + (c0 + fn * 16)] = (bf16)acc[fm][fn][r];
}

// ---------------------------------------------------------------------------
// GEMM2 (unchanged control): C_f32[M][N] = A_bf16[M][K] @ B_bf16[N][K]^T
// ---------------------------------------------------------------------------
__global__ __launch_bounds__(256) void gemm2_bt(const bf16* __restrict__ A,
                                                const bf16* __restrict__ B,
                                                float* __restrict__ out,
                                                int M, int N, int K) {
    __shared__ bf16 Al[128 * 64];
    __shared__ bf16 Bl[128 * 64];

    const int t  = threadIdx.x;
    const int l  = t & 63;
    const int w  = t >> 6;
    const int wr = w >> 1, wc = w & 1;
    const int lr = l & 15;
    const int kg = l >> 4;

    const int nwg = gridDim.x;
    const int bid = blockIdx.x;
    const int cpx = nwg >> 3;
    const int swz = (bid & 7) * cpx + (bid >> 3);
    const int ntn = N >> 7;
    const int tm  = (swz / ntn) << 7;
    const int tn  = (swz % ntn) << 7;

    f32x4 acc[4][4] = {};

    for (int kt = 0; kt < K; kt += 64) {
#pragma unroll
        for (int c = 0; c < 4; ++c) {
            int i = c * 256 + t;
            gload_lds16(A + (size_t)(tm + (i >> 3)) * K + kt + (i & 7) * 8, &Al[i * 8]);
        }
#pragma unroll
        for (int c = 0; c < 4; ++c) {
            int i = c * 256 + t;
            gload_lds16(B + (size_t)(tn + (i >> 3)) * K + kt + (i & 7) * 8, &Bl[i * 8]);
        }
        __syncthreads();

#pragma unroll
        for (int ks = 0; ks < 2; ++ks) {
            bf16x8 af[4], bfr[4];
#pragma unroll
            for (int f = 0; f < 4; ++f) {
                af[f]  = *(const bf16x8*)&Al[(wr * 64 + f * 16 + lr) * 64 + ks * 32 + kg * 8];
                bfr[f] = *(const bf16x8*)&Bl[(wc * 64 + f * 16 + lr) * 64 + ks * 32 + kg * 8];
            }
#pragma unroll
            for (int fm = 0; fm < 4; ++fm)
#pragma unroll
                for (int fn = 0; fn < 4; ++fn)
                    acc[fm][fn] = __builtin_amdgcn_mfma_f32_16x16x32_bf16(
                        af[fm], bfr[fn], acc[fm][fn], 0, 0, 0);
        }
        __syncthreads();
    }

    const int r0 = tm + wr * 64 + kg * 4;
    const int c0 = tn + wc * 64 + lr;
#pragma unroll
    for (int fm = 0; fm < 4; ++fm)
#pragma unroll
        for (int fn = 0; fn < 4; ++fn)
#pragma unroll
            for (int r = 0; r < 4; ++r)
                out[(size_t)(r0 + fm * 16 + r) * N + (c0 + fn * 16)] = acc[fm][fn][r];
}

// ---------------------------------------------------------------------------
extern "C" void kernel_launch(void* const* d_in, const int* in_sizes, int n_in,
                              void* d_out, int out_size, void* d_ws, size_t ws_size,
                              hipStream_t stream) {
    const float* x  = (const float*)d_in[0];  // [16384][4096]
    const float* U  = (const float*)d_in[1];  // [4096][512]
    const float* sg = (const float*)d_in[2];  // [512]
    const float* V  = (const float*)d_in[3];  // [4096][512]
    float* out = (float*)d_out;               // [16384][4096] f32

    char* ws = (char*)d_ws;
    bf16* Vst = (bf16*)ws;                    // [512][4096]  = 4 MB (pre-swizzled)
    bf16* Ub  = (bf16*)(ws + (4u << 20));     // [4096][512]  = 4 MB
    bf16* T   = (bf16*)(ws + (8u << 20));     // [16384][512] = 16 MB

    vt_scale<<<dim3(D_IN / 64, RANK / 64), 256, 0, stream>>>(V, sg, Vst);
    cvt_bf16_4<<<(D_OUT * RANK / 4 + 255) / 256, 256, 0, stream>>>(U, Ub, D_OUT * RANK / 4);

    // GEMM1: T = bf16( x @ Vst^T ), grid 128*4 = 512 blocks
    gemm1_swz<<<(TOKENS / 128) * (RANK / 128), 256, 0, stream>>>(
        x, Vst, T, TOKENS, RANK, D_IN);

    // GEMM2: out = T @ Ub^T (f32 out), grid 128*32 = 4096 blocks
    gemm2_bt<<<(TOKENS / 128) * (D_OUT / 128), 256, 0, stream>>>(
        T, Ub, out, TOKENS, D_OUT, RANK);
}